// Round 1
// baseline (2410.617 us; speedup 1.0000x reference)
//
#include <hip/hip_runtime.h>

#define N_NODES 100000
#define N_EDGES 1600000
#define HID 64
#define EDIM 32
#define BN_EPS 1e-5f

// ---------------------------------------------------------------------------
// Edge kernel: one wave per edge.  lane = output feature (0..63).
// We column kept in 32 VGPRs (loaded once per wave); edge_attr row read via
// 8 broadcast float4 loads; 32 v_fmac per edge; gather x[src], relu,
// atomicAdd into agg[dst].
// ---------------------------------------------------------------------------
__global__ __launch_bounds__(256) void edge_kernel(
    const float* __restrict__ x, const float* __restrict__ eattr,
    const int* __restrict__ src, const int* __restrict__ dst,
    const float* __restrict__ We, const float* __restrict__ be,
    float* __restrict__ agg)
{
    const int lane = threadIdx.x & 63;

    float w[EDIM];
#pragma unroll
    for (int k = 0; k < EDIM; ++k) w[k] = We[k * HID + lane];
    const float bias = be[lane];

    const int wid = (int)((blockIdx.x * blockDim.x + threadIdx.x) >> 6);
    const int nw  = (int)((gridDim.x * blockDim.x) >> 6);

    for (int e = wid; e < N_EDGES; e += nw) {
        const float4* p = (const float4*)(eattr + (size_t)e * EDIM);
        float a[EDIM];
#pragma unroll
        for (int j = 0; j < EDIM / 4; ++j) {
            float4 t = p[j];
            a[4 * j + 0] = t.x; a[4 * j + 1] = t.y;
            a[4 * j + 2] = t.z; a[4 * j + 3] = t.w;
        }
        const int s = src[e];
        const int d = dst[e];

        float acc = bias;
#pragma unroll
        for (int k = 0; k < EDIM; ++k) acc = fmaf(a[k], w[k], acc);

        float m = x[(size_t)s * HID + lane] + acc;
        m = fmaxf(m, 0.0f);
        atomicAdd(&agg[(size_t)d * HID + lane], m);
    }
}

// ---------------------------------------------------------------------------
// MLP kernel: lane = node (64 nodes per wave).  h = x + agg in 64 VGPRs,
// weights fetched through wave-uniform addresses (scalar loads),
// u = relu(h@W1+b1)@W2+b2 written to uout (pre-BN buffer).
// ---------------------------------------------------------------------------
__global__ __launch_bounds__(256) void mlp_kernel(
    const float* __restrict__ xin, const float* __restrict__ agg,
    const float* __restrict__ W1, const float* __restrict__ b1,
    const float* __restrict__ W2, const float* __restrict__ b2,
    float* __restrict__ uout)
{
    const int lane = threadIdx.x & 63;
    const int wid  = (int)((blockIdx.x * blockDim.x + threadIdx.x) >> 6);
    const int n    = wid * 64 + lane;
    const bool ok  = (n < N_NODES);
    const size_t base = (size_t)n * HID;

    float h[HID];
    if (ok) {
        const float4* px = (const float4*)(xin + base);
        const float4* pa = (const float4*)(agg + base);
#pragma unroll
        for (int j = 0; j < HID / 4; ++j) {
            float4 xv = px[j];
            float4 av = pa[j];
            h[4 * j + 0] = xv.x + av.x;
            h[4 * j + 1] = xv.y + av.y;
            h[4 * j + 2] = xv.z + av.z;
            h[4 * j + 3] = xv.w + av.w;
        }
    } else {
#pragma unroll
        for (int k = 0; k < HID; ++k) h[k] = 0.0f;
    }

    float u[HID];
#pragma unroll
    for (int f = 0; f < HID; ++f) u[f] = b2[f];

    for (int c = 0; c < 4; ++c) {           // 16-feature chunks of the hidden layer
        float t[16];
#pragma unroll
        for (int j = 0; j < 16; ++j) t[j] = b1[c * 16 + j];
#pragma unroll
        for (int k = 0; k < HID; ++k) {
            const float hk = h[k];
#pragma unroll
            for (int j = 0; j < 16; ++j)
                t[j] = fmaf(hk, W1[k * HID + c * 16 + j], t[j]);
        }
#pragma unroll
        for (int j = 0; j < 16; ++j) t[j] = fmaxf(t[j], 0.0f);
#pragma unroll
        for (int j = 0; j < 16; ++j) {
            const float tj = t[j];
#pragma unroll
            for (int f = 0; f < HID; ++f)
                u[f] = fmaf(tj, W2[(c * 16 + j) * HID + f], u[f]);
        }
    }

    if (ok) {
        float4* po = (float4*)(uout + base);
#pragma unroll
        for (int j = 0; j < HID / 4; ++j)
            po[j] = make_float4(u[4 * j], u[4 * j + 1], u[4 * j + 2], u[4 * j + 3]);
    }
}

// ---------------------------------------------------------------------------
// Final projection: out = x @ Wout + bout (no relu / BN)
// ---------------------------------------------------------------------------
__global__ __launch_bounds__(256) void out_kernel(
    const float* __restrict__ xin, const float* __restrict__ Wo,
    const float* __restrict__ bo, float* __restrict__ out)
{
    const int lane = threadIdx.x & 63;
    const int wid  = (int)((blockIdx.x * blockDim.x + threadIdx.x) >> 6);
    const int n    = wid * 64 + lane;
    const bool ok  = (n < N_NODES);
    const size_t base = (size_t)n * HID;

    float h[HID];
    if (ok) {
        const float4* px = (const float4*)(xin + base);
#pragma unroll
        for (int j = 0; j < HID / 4; ++j) {
            float4 xv = px[j];
            h[4 * j + 0] = xv.x; h[4 * j + 1] = xv.y;
            h[4 * j + 2] = xv.z; h[4 * j + 3] = xv.w;
        }
    } else {
#pragma unroll
        for (int k = 0; k < HID; ++k) h[k] = 0.0f;
    }

    for (int c = 0; c < 4; ++c) {
        float t[16];
#pragma unroll
        for (int j = 0; j < 16; ++j) t[j] = bo[c * 16 + j];
#pragma unroll
        for (int k = 0; k < HID; ++k) {
            const float hk = h[k];
#pragma unroll
            for (int j = 0; j < 16; ++j)
                t[j] = fmaf(hk, Wo[k * HID + c * 16 + j], t[j]);
        }
        if (ok) {
            float4* po = (float4*)(out + base + c * 16);
#pragma unroll
            for (int j = 0; j < 4; ++j)
                po[j] = make_float4(t[4 * j], t[4 * j + 1], t[4 * j + 2], t[4 * j + 3]);
        }
    }
}

// ---------------------------------------------------------------------------
// BN statistics: coalesced (lane = feature), per-thread running sums over a
// strided node range, block LDS reduce (4 waves -> 1), one atomic per feature
// per block.  stats[0..63] = sum, stats[64..127] = sum of squares.
// ---------------------------------------------------------------------------
__global__ __launch_bounds__(256) void stats_kernel(
    const float* __restrict__ u, float* __restrict__ stats)
{
    __shared__ float ls[256];
    __shared__ float ls2[256];
    const int tid = threadIdx.x;
    const int g   = (int)(blockIdx.x * 256 + tid);
    const int f   = g & 63;
    const int row = g >> 6;
    const int rstride = (int)((gridDim.x * 256) >> 6);

    float s = 0.0f, s2 = 0.0f;
    for (int n = row; n < N_NODES; n += rstride) {
        float v = u[(size_t)n * HID + f];
        s += v;
        s2 = fmaf(v, v, s2);
    }
    ls[tid] = s;
    ls2[tid] = s2;
    __syncthreads();
    if (tid < 64) {
        float a = ls[tid] + ls[tid + 64] + ls[tid + 128] + ls[tid + 192];
        float b = ls2[tid] + ls2[tid + 64] + ls2[tid + 128] + ls2[tid + 192];
        atomicAdd(&stats[tid], a);
        atomicAdd(&stats[64 + tid], b);
    }
}

// ---------------------------------------------------------------------------
// BN apply + relu: x_out = relu((u - mean) * rsqrt(var+eps) * gamma + beta)
// Elementwise float4 grid-stride; per-thread feature block is loop-invariant.
// ---------------------------------------------------------------------------
__global__ __launch_bounds__(256) void bn_relu_kernel(
    const float* __restrict__ u, const float* __restrict__ stats,
    const float* __restrict__ gamma, const float* __restrict__ beta,
    float* __restrict__ xout)
{
    const int total4 = N_NODES * HID / 4;
    int i = (int)(blockIdx.x * blockDim.x + threadIdx.x);
    const int stride = (int)(gridDim.x * blockDim.x);   // multiple of 16 float4s
    const int fb = (i * 4) & 63;

    const float invN = 1.0f / (float)N_NODES;
    float sc[4], sh[4];
#pragma unroll
    for (int j = 0; j < 4; ++j) {
        float mean = stats[fb + j] * invN;
        float var  = stats[64 + fb + j] * invN - mean * mean;
        float s    = gamma[fb + j] * rsqrtf(var + BN_EPS);
        sc[j] = s;
        sh[j] = beta[fb + j] - mean * s;
    }
    for (; i < total4; i += stride) {
        float4 v = ((const float4*)u)[i];
        v.x = fmaxf(fmaf(v.x, sc[0], sh[0]), 0.0f);
        v.y = fmaxf(fmaf(v.y, sc[1], sh[1]), 0.0f);
        v.z = fmaxf(fmaf(v.z, sc[2], sh[2]), 0.0f);
        v.w = fmaxf(fmaf(v.w, sc[3], sh[3]), 0.0f);
        ((float4*)xout)[i] = v;
    }
}

// ---------------------------------------------------------------------------
extern "C" void kernel_launch(void* const* d_in, const int* in_sizes, int n_in,
                              void* d_out, int out_size, void* d_ws, size_t ws_size,
                              hipStream_t stream)
{
    const float* x0    = (const float*)d_in[0];
    const int*   eidx  = (const int*)d_in[1];
    const float* eattr = (const float*)d_in[2];
    const float* We    = (const float*)d_in[3];
    const float* be    = (const float*)d_in[4];
    const float* W1    = (const float*)d_in[5];
    const float* b1    = (const float*)d_in[6];
    const float* W2    = (const float*)d_in[7];
    const float* b2    = (const float*)d_in[8];
    const float* gamma = (const float*)d_in[9];
    const float* beta  = (const float*)d_in[10];
    const float* Wout  = (const float*)d_in[11];
    const float* bout  = (const float*)d_in[12];
    float* out = (float*)d_out;

    const size_t NH = (size_t)N_NODES * HID;
    float* A     = (float*)d_ws;        // post-layer x
    float* AGG   = A + NH;              // scatter-add accumulator
    float* stats = AGG + NH;            // 128 floats: sum / sumsq
    float* B     = out;                 // pre-BN MLP output (d_out reused as scratch)

    const int mlp_blocks = ((N_NODES + 63) / 64 + 3) / 4;   // 391

    const float* xin = x0;
    for (int i = 0; i < 3; ++i) {
        hipMemsetAsync(AGG, 0, NH * sizeof(float), stream);
        hipMemsetAsync(stats, 0, 128 * sizeof(float), stream);

        edge_kernel<<<2048, 256, 0, stream>>>(
            xin, eattr, eidx, eidx + N_EDGES,
            We + (size_t)i * EDIM * HID, be + (size_t)i * HID, AGG);

        mlp_kernel<<<mlp_blocks, 256, 0, stream>>>(
            xin, AGG,
            W1 + (size_t)i * HID * HID, b1 + (size_t)i * HID,
            W2 + (size_t)i * HID * HID, b2 + (size_t)i * HID, B);

        stats_kernel<<<256, 256, 0, stream>>>(B, stats);

        bn_relu_kernel<<<1024, 256, 0, stream>>>(
            B, stats, gamma + (size_t)i * HID, beta + (size_t)i * HID, A);

        xin = A;
    }

    out_kernel<<<mlp_blocks, 256, 0, stream>>>(A, Wout, bout, out);
}

// Round 2
// 2306.902 us; speedup vs baseline: 1.0450x; 1.0450x over previous
//
#include <hip/hip_runtime.h>

#define N_NODES 100000
#define N_EDGES 1600000
#define HID 64
#define EDIM 32
#define BN_EPS 1e-5f

#define SCAN_CHUNK 1024
#define NB_SCAN ((N_NODES + SCAN_CHUNK - 1) / SCAN_CHUNK)   // 98

// ---------------------------------------------------------------------------
// Counting sort of edges by dst.  Built once per call, reused by all 3 layers.
// ---------------------------------------------------------------------------
__global__ __launch_bounds__(256) void hist_kernel(
    const int* __restrict__ dst, int* __restrict__ cnt)
{
    int i = (int)(blockIdx.x * blockDim.x + threadIdx.x);
    const int stride = (int)(gridDim.x * blockDim.x);
    for (; i < N_EDGES; i += stride) atomicAdd(&cnt[dst[i]], 1);
}

// per-1024-element block sums
__global__ __launch_bounds__(256) void scan1_kernel(
    const int* __restrict__ cnt, int* __restrict__ bsum)
{
    __shared__ int s[256];
    const int b = (int)blockIdx.x, t = (int)threadIdx.x;
    const int base = b * SCAN_CHUNK + t * 4;
    int sum = 0;
#pragma unroll
    for (int k = 0; k < 4; ++k) {
        int idx = base + k;
        if (idx < N_NODES) sum += cnt[idx];
    }
    s[t] = sum;
    __syncthreads();
    for (int off = 128; off > 0; off >>= 1) {
        if (t < off) s[t] += s[t + off];
        __syncthreads();
    }
    if (t == 0) bsum[b] = s[0];
}

// exclusive scan of the 98 block sums (single block)
__global__ __launch_bounds__(128) void scan2_kernel(
    const int* __restrict__ bsum, int* __restrict__ bofs, int* __restrict__ row_ptr)
{
    __shared__ int s[128];
    const int t = (int)threadIdx.x;
    const int v = (t < NB_SCAN) ? bsum[t] : 0;
    s[t] = v;
    __syncthreads();
    for (int off = 1; off < 128; off <<= 1) {
        int add = (t >= off) ? s[t - off] : 0;
        __syncthreads();
        s[t] += add;
        __syncthreads();
    }
    if (t < NB_SCAN) bofs[t] = s[t] - v;          // exclusive prefix
    if (t == NB_SCAN - 1) row_ptr[N_NODES] = s[t]; // total == N_EDGES
}

// final exclusive scan -> row_ptr (and a working copy in pos)
__global__ __launch_bounds__(256) void scan3_kernel(
    const int* __restrict__ cnt, const int* __restrict__ bofs,
    int* __restrict__ row_ptr, int* __restrict__ pos)
{
    __shared__ int s[256];
    const int b = (int)blockIdx.x, t = (int)threadIdx.x;
    const int base = b * SCAN_CHUNK + t * 4;
    int v[4];
    int sum = 0;
#pragma unroll
    for (int k = 0; k < 4; ++k) {
        int idx = base + k;
        v[k] = (idx < N_NODES) ? cnt[idx] : 0;
        sum += v[k];
    }
    s[t] = sum;
    __syncthreads();
    for (int off = 1; off < 256; off <<= 1) {
        int add = (t >= off) ? s[t - off] : 0;
        __syncthreads();
        s[t] += add;
        __syncthreads();
    }
    int run = s[t] - sum + bofs[b];   // exclusive prefix for this thread's chunk
#pragma unroll
    for (int k = 0; k < 4; ++k) {
        int idx = base + k;
        if (idx < N_NODES) {
            row_ptr[idx] = run;
            pos[idx] = run;
            run += v[k];
        }
    }
}

// bucket-scatter: perm_e[p] = edge id, perm_src[p] = its source node
__global__ __launch_bounds__(256) void scatter_kernel(
    const int* __restrict__ src, const int* __restrict__ dst,
    int* __restrict__ pos, int* __restrict__ perm_e, int* __restrict__ perm_src)
{
    int i = (int)(blockIdx.x * blockDim.x + threadIdx.x);
    const int stride = (int)(gridDim.x * blockDim.x);
    for (; i < N_EDGES; i += stride) {
        const int d = dst[i];
        const int p = atomicAdd(&pos[d], 1);
        perm_e[p] = i;
        perm_src[p] = src[i];
    }
}

// ---------------------------------------------------------------------------
// Segmented edge-message sum: one wave per dst node, lane = feature.
// agg[n] = sum_{edges e->n} relu(x[src] + eattr[e] @ We + be).  No atomics.
// ---------------------------------------------------------------------------
__global__ __launch_bounds__(256) void gather_kernel(
    const float* __restrict__ x, const float* __restrict__ eattr,
    const int* __restrict__ row_ptr, const int* __restrict__ perm_e,
    const int* __restrict__ perm_src,
    const float* __restrict__ We, const float* __restrict__ be,
    float* __restrict__ agg)
{
    const int lane = threadIdx.x & 63;
    const int wid  = (int)((blockIdx.x * blockDim.x + threadIdx.x) >> 6);
    if (wid >= N_NODES) return;

    float w[EDIM];
#pragma unroll
    for (int k = 0; k < EDIM; ++k) w[k] = We[k * HID + lane];
    const float bias = be[lane];

    const int begin = row_ptr[wid];
    const int end   = row_ptr[wid + 1];

    float sum = 0.0f;
    for (int j = begin; j < end; ++j) {
        const int e = perm_e[j];
        const int s = perm_src[j];
        const float4* p = (const float4*)(eattr + (size_t)e * EDIM);
        float4 q[EDIM / 4];
#pragma unroll
        for (int jj = 0; jj < EDIM / 4; ++jj) q[jj] = p[jj];

        float acc = bias;
#pragma unroll
        for (int jj = 0; jj < EDIM / 4; ++jj) {
            acc = fmaf(q[jj].x, w[4 * jj + 0], acc);
            acc = fmaf(q[jj].y, w[4 * jj + 1], acc);
            acc = fmaf(q[jj].z, w[4 * jj + 2], acc);
            acc = fmaf(q[jj].w, w[4 * jj + 3], acc);
        }
        const float m = x[(size_t)s * HID + lane] + acc;
        sum += fmaxf(m, 0.0f);
    }
    agg[(size_t)wid * HID + lane] = sum;
}

// ---------------------------------------------------------------------------
// MLP kernel: lane = node.  u = relu((x+agg)@W1+b1)@W2+b2
// ---------------------------------------------------------------------------
__global__ __launch_bounds__(256) void mlp_kernel(
    const float* __restrict__ xin, const float* __restrict__ agg,
    const float* __restrict__ W1, const float* __restrict__ b1,
    const float* __restrict__ W2, const float* __restrict__ b2,
    float* __restrict__ uout)
{
    const int lane = threadIdx.x & 63;
    const int wid  = (int)((blockIdx.x * blockDim.x + threadIdx.x) >> 6);
    const int n    = wid * 64 + lane;
    const bool ok  = (n < N_NODES);
    const size_t base = (size_t)n * HID;

    float h[HID];
    if (ok) {
        const float4* px = (const float4*)(xin + base);
        const float4* pa = (const float4*)(agg + base);
#pragma unroll
        for (int j = 0; j < HID / 4; ++j) {
            float4 xv = px[j];
            float4 av = pa[j];
            h[4 * j + 0] = xv.x + av.x;
            h[4 * j + 1] = xv.y + av.y;
            h[4 * j + 2] = xv.z + av.z;
            h[4 * j + 3] = xv.w + av.w;
        }
    } else {
#pragma unroll
        for (int k = 0; k < HID; ++k) h[k] = 0.0f;
    }

    float u[HID];
#pragma unroll
    for (int f = 0; f < HID; ++f) u[f] = b2[f];

    for (int c = 0; c < 4; ++c) {
        float t[16];
#pragma unroll
        for (int j = 0; j < 16; ++j) t[j] = b1[c * 16 + j];
#pragma unroll
        for (int k = 0; k < HID; ++k) {
            const float hk = h[k];
#pragma unroll
            for (int j = 0; j < 16; ++j)
                t[j] = fmaf(hk, W1[k * HID + c * 16 + j], t[j]);
        }
#pragma unroll
        for (int j = 0; j < 16; ++j) t[j] = fmaxf(t[j], 0.0f);
#pragma unroll
        for (int j = 0; j < 16; ++j) {
            const float tj = t[j];
#pragma unroll
            for (int f = 0; f < HID; ++f)
                u[f] = fmaf(tj, W2[(c * 16 + j) * HID + f], u[f]);
        }
    }

    if (ok) {
        float4* po = (float4*)(uout + base);
#pragma unroll
        for (int j = 0; j < HID / 4; ++j)
            po[j] = make_float4(u[4 * j], u[4 * j + 1], u[4 * j + 2], u[4 * j + 3]);
    }
}

// ---------------------------------------------------------------------------
// Final projection: out = x @ Wout + bout
// ---------------------------------------------------------------------------
__global__ __launch_bounds__(256) void out_kernel(
    const float* __restrict__ xin, const float* __restrict__ Wo,
    const float* __restrict__ bo, float* __restrict__ out)
{
    const int lane = threadIdx.x & 63;
    const int wid  = (int)((blockIdx.x * blockDim.x + threadIdx.x) >> 6);
    const int n    = wid * 64 + lane;
    const bool ok  = (n < N_NODES);
    const size_t base = (size_t)n * HID;

    float h[HID];
    if (ok) {
        const float4* px = (const float4*)(xin + base);
#pragma unroll
        for (int j = 0; j < HID / 4; ++j) {
            float4 xv = px[j];
            h[4 * j + 0] = xv.x; h[4 * j + 1] = xv.y;
            h[4 * j + 2] = xv.z; h[4 * j + 3] = xv.w;
        }
    } else {
#pragma unroll
        for (int k = 0; k < HID; ++k) h[k] = 0.0f;
    }

    for (int c = 0; c < 4; ++c) {
        float t[16];
#pragma unroll
        for (int j = 0; j < 16; ++j) t[j] = bo[c * 16 + j];
#pragma unroll
        for (int k = 0; k < HID; ++k) {
            const float hk = h[k];
#pragma unroll
            for (int j = 0; j < 16; ++j)
                t[j] = fmaf(hk, Wo[k * HID + c * 16 + j], t[j]);
        }
        if (ok) {
            float4* po = (float4*)(out + base + c * 16);
#pragma unroll
            for (int j = 0; j < 4; ++j)
                po[j] = make_float4(t[4 * j], t[4 * j + 1], t[4 * j + 2], t[4 * j + 3]);
        }
    }
}

// ---------------------------------------------------------------------------
// BN statistics (sum / sumsq per feature)
// ---------------------------------------------------------------------------
__global__ __launch_bounds__(256) void stats_kernel(
    const float* __restrict__ u, float* __restrict__ stats)
{
    __shared__ float ls[256];
    __shared__ float ls2[256];
    const int tid = (int)threadIdx.x;
    const int g   = (int)(blockIdx.x * 256 + tid);
    const int f   = g & 63;
    const int row = g >> 6;
    const int rstride = (int)((gridDim.x * 256) >> 6);

    float s = 0.0f, s2 = 0.0f;
    for (int n = row; n < N_NODES; n += rstride) {
        float v = u[(size_t)n * HID + f];
        s += v;
        s2 = fmaf(v, v, s2);
    }
    ls[tid] = s;
    ls2[tid] = s2;
    __syncthreads();
    if (tid < 64) {
        float a = ls[tid] + ls[tid + 64] + ls[tid + 128] + ls[tid + 192];
        float b = ls2[tid] + ls2[tid + 64] + ls2[tid + 128] + ls2[tid + 192];
        atomicAdd(&stats[tid], a);
        atomicAdd(&stats[64 + tid], b);
    }
}

// ---------------------------------------------------------------------------
// BN apply + relu
// ---------------------------------------------------------------------------
__global__ __launch_bounds__(256) void bn_relu_kernel(
    const float* __restrict__ u, const float* __restrict__ stats,
    const float* __restrict__ gamma, const float* __restrict__ beta,
    float* __restrict__ xout)
{
    const int total4 = N_NODES * HID / 4;
    int i = (int)(blockIdx.x * blockDim.x + threadIdx.x);
    const int stride = (int)(gridDim.x * blockDim.x);   // multiple of 16 float4s
    const int fb = (i * 4) & 63;

    const float invN = 1.0f / (float)N_NODES;
    float sc[4], sh[4];
#pragma unroll
    for (int j = 0; j < 4; ++j) {
        float mean = stats[fb + j] * invN;
        float var  = stats[64 + fb + j] * invN - mean * mean;
        float s    = gamma[fb + j] * rsqrtf(var + BN_EPS);
        sc[j] = s;
        sh[j] = beta[fb + j] - mean * s;
    }
    for (; i < total4; i += stride) {
        float4 v = ((const float4*)u)[i];
        v.x = fmaxf(fmaf(v.x, sc[0], sh[0]), 0.0f);
        v.y = fmaxf(fmaf(v.y, sc[1], sh[1]), 0.0f);
        v.z = fmaxf(fmaf(v.z, sc[2], sh[2]), 0.0f);
        v.w = fmaxf(fmaf(v.w, sc[3], sh[3]), 0.0f);
        ((float4*)xout)[i] = v;
    }
}

// ---------------------------------------------------------------------------
extern "C" void kernel_launch(void* const* d_in, const int* in_sizes, int n_in,
                              void* d_out, int out_size, void* d_ws, size_t ws_size,
                              hipStream_t stream)
{
    const float* x0    = (const float*)d_in[0];
    const int*   eidx  = (const int*)d_in[1];
    const float* eattr = (const float*)d_in[2];
    const float* We    = (const float*)d_in[3];
    const float* be    = (const float*)d_in[4];
    const float* W1    = (const float*)d_in[5];
    const float* b1    = (const float*)d_in[6];
    const float* W2    = (const float*)d_in[7];
    const float* b2    = (const float*)d_in[8];
    const float* gamma = (const float*)d_in[9];
    const float* beta  = (const float*)d_in[10];
    const float* Wout  = (const float*)d_in[11];
    const float* bout  = (const float*)d_in[12];
    float* out = (float*)d_out;

    const int* src = eidx;
    const int* dst = eidx + N_EDGES;

    const size_t NH = (size_t)N_NODES * HID;

    // workspace layout (fp32/int32 elements)
    float* A     = (float*)d_ws;                 // post-layer x        (NH)
    float* AGG   = A + NH;                       // segmented sums      (NH)
    float* stats = AGG + NH;                     // 128 floats
    int* cnt      = (int*)(stats + 128);         // N_NODES
    int* bsum     = cnt + N_NODES;               // NB_SCAN (pad 128)
    int* bofs     = bsum + 128;                  // NB_SCAN (pad 128)
    int* row_ptr  = bofs + 128;                  // N_NODES + 1
    int* pos      = row_ptr + N_NODES + 1;       // N_NODES
    int* perm_e   = pos + N_NODES;               // N_EDGES
    int* perm_src = perm_e + N_EDGES;            // N_EDGES
    float* B = out;                              // pre-BN MLP output (reuse d_out)

    // ---- build CSR-by-dst (once; shared by all 3 layers) ----
    hipMemsetAsync(cnt, 0, N_NODES * sizeof(int), stream);
    hist_kernel<<<1024, 256, 0, stream>>>(dst, cnt);
    scan1_kernel<<<NB_SCAN, 256, 0, stream>>>(cnt, bsum);
    scan2_kernel<<<1, 128, 0, stream>>>(bsum, bofs, row_ptr);
    scan3_kernel<<<NB_SCAN, 256, 0, stream>>>(cnt, bofs, row_ptr, pos);
    scatter_kernel<<<1024, 256, 0, stream>>>(src, dst, pos, perm_e, perm_src);

    const int mlp_blocks    = ((N_NODES + 63) / 64 + 3) / 4;       // 391
    const int gather_blocks = (N_NODES + 3) / 4;                   // 25000 (4 waves/block)

    const float* xin = x0;
    for (int i = 0; i < 3; ++i) {
        hipMemsetAsync(stats, 0, 128 * sizeof(float), stream);

        gather_kernel<<<gather_blocks, 256, 0, stream>>>(
            xin, eattr, row_ptr, perm_e, perm_src,
            We + (size_t)i * EDIM * HID, be + (size_t)i * HID, AGG);

        mlp_kernel<<<mlp_blocks, 256, 0, stream>>>(
            xin, AGG,
            W1 + (size_t)i * HID * HID, b1 + (size_t)i * HID,
            W2 + (size_t)i * HID * HID, b2 + (size_t)i * HID, B);

        stats_kernel<<<256, 256, 0, stream>>>(B, stats);

        bn_relu_kernel<<<1024, 256, 0, stream>>>(
            B, stats, gamma + (size_t)i * HID, beta + (size_t)i * HID, A);

        xin = A;
    }

    out_kernel<<<mlp_blocks, 256, 0, stream>>>(A, Wout, bout, out);
}